// Round 2
// baseline (688.127 us; speedup 1.0000x reference)
//
#include <hip/hip_runtime.h>

typedef __bf16 bf16x8 __attribute__((ext_vector_type(8)));
typedef float f32x4 __attribute__((ext_vector_type(4)));
typedef unsigned short u16x8 __attribute__((ext_vector_type(8)));
typedef unsigned short u16x4 __attribute__((ext_vector_type(4)));

__device__ __forceinline__ unsigned short f2bf(float f) {
    union { float f; unsigned int u; } a; a.f = f;
    unsigned int u = a.u;
    unsigned int r = (u + 0x7FFFu + ((u >> 16) & 1u)) >> 16;  // RNE
    return (unsigned short)r;
}

// ---------------- LayerNorm: fp32 in -> bf16 out (E=1024, one row per block) ----------------
__global__ __launch_bounds__(256) void ln_kernel(
    const float* __restrict__ x, const float* __restrict__ g,
    const float* __restrict__ b, unsigned short* __restrict__ out)
{
    const int row = blockIdx.x;
    const int tid = threadIdx.x;
    const float4 v = reinterpret_cast<const float4*>(x + (size_t)row * 1024)[tid];
    float s = v.x + v.y + v.z + v.w;
    float q = v.x * v.x + v.y * v.y + v.z * v.z + v.w * v.w;
#pragma unroll
    for (int off = 32; off >= 1; off >>= 1) {
        s += __shfl_xor(s, off);
        q += __shfl_xor(q, off);
    }
    __shared__ float ss[4], sq[4];
    const int wid = tid >> 6, lane = tid & 63;
    if (lane == 0) { ss[wid] = s; sq[wid] = q; }
    __syncthreads();
    s = ss[0] + ss[1] + ss[2] + ss[3];
    q = sq[0] + sq[1] + sq[2] + sq[3];
    const float mu = s * (1.0f / 1024.0f);
    const float var = q * (1.0f / 1024.0f) - mu * mu;
    const float rs = rsqrtf(var + 1e-5f);
    const float4 gv = reinterpret_cast<const float4*>(g)[tid];
    const float4 bv = reinterpret_cast<const float4*>(b)[tid];
    u16x4 o;
    o[0] = f2bf((v.x - mu) * rs * gv.x + bv.x);
    o[1] = f2bf((v.y - mu) * rs * gv.y + bv.y);
    o[2] = f2bf((v.z - mu) * rs * gv.z + bv.z);
    o[3] = f2bf((v.w - mu) * rs * gv.w + bv.w);
    reinterpret_cast<u16x4*>(out + (size_t)row * 1024)[tid] = o;
}

// ---------------- Weight convert + transpose: W[K][N] fp32 -> Wt[N][K] bf16 ----------------
__global__ __launch_bounds__(256) void convT_kernel(
    const float* __restrict__ W, unsigned short* __restrict__ Wt, int K, int N)
{
    __shared__ float t[32][33];
    const int n0 = blockIdx.x * 32, k0 = blockIdx.y * 32;
    const int tx = threadIdx.x & 31;
    const int ty = threadIdx.x >> 5;  // 0..7
#pragma unroll
    for (int i = 0; i < 4; i++)
        t[ty + 8 * i][tx] = W[(size_t)(k0 + ty + 8 * i) * N + (n0 + tx)];
    __syncthreads();
#pragma unroll
    for (int i = 0; i < 4; i++)
        Wt[(size_t)(n0 + ty + 8 * i) * K + (k0 + tx)] = f2bf(t[tx][ty + 8 * i]);
}

// ---------------- bf16 MFMA GEMM: C[M][N] = A[M][K] * Wt[N][K]^T, fused epilogues ----------------
// EPI 0: out bf16          EPI 1: out fp32 = acc + resid
// EPI 2: out bf16 = gelu(acc + bias)      EPI 3: out fp32 = acc + bias + resid
template <int EPI>
__global__ __launch_bounds__(256) void gemm_kernel(
    const unsigned short* __restrict__ A, const unsigned short* __restrict__ Bt,
    const float* __restrict__ bias, const float* __restrict__ resid,
    void* __restrict__ out, int M, int N, int K)
{
    __shared__ unsigned short Al[128][72];
    __shared__ unsigned short Bl[128][72];
    const int tid = threadIdx.x;
    const int lane = tid & 63, wid = tid >> 6;
    const int wr = wid >> 1, wc = wid & 1;      // 2x2 waves over 128x128
    const int li = lane & 15, lg = lane >> 4;
    const int m0 = blockIdx.y * 128, n0 = blockIdx.x * 128;
    const int sr = tid >> 3;                    // 0..31 staging row
    const int sc = (tid & 7) * 8;               // 0..56 staging col
    f32x4 acc[4][4] = {};

    for (int k0 = 0; k0 < K; k0 += 64) {
        __syncthreads();
#pragma unroll
        for (int i = 0; i < 4; i++) {
            const int r = sr + 32 * i;
            *reinterpret_cast<u16x8*>(&Al[r][sc]) =
                *reinterpret_cast<const u16x8*>(&A[(size_t)(m0 + r) * K + k0 + sc]);
            *reinterpret_cast<u16x8*>(&Bl[r][sc]) =
                *reinterpret_cast<const u16x8*>(&Bt[(size_t)(n0 + r) * K + k0 + sc]);
        }
        __syncthreads();
#pragma unroll
        for (int ks = 0; ks < 2; ks++) {
            const int kof = ks * 32 + lg * 8;
            bf16x8 af[4], bfr[4];
#pragma unroll
            for (int m = 0; m < 4; m++)
                af[m] = *reinterpret_cast<const bf16x8*>(&Al[wr * 64 + m * 16 + li][kof]);
#pragma unroll
            for (int n = 0; n < 4; n++)
                bfr[n] = *reinterpret_cast<const bf16x8*>(&Bl[wc * 64 + n * 16 + li][kof]);
#pragma unroll
            for (int m = 0; m < 4; m++)
#pragma unroll
                for (int n = 0; n < 4; n++)
                    acc[m][n] = __builtin_amdgcn_mfma_f32_16x16x32_bf16(af[m], bfr[n], acc[m][n], 0, 0, 0);
        }
    }

#pragma unroll
    for (int m = 0; m < 4; m++) {
#pragma unroll
        for (int r = 0; r < 4; r++) {
            const int row = m0 + wr * 64 + m * 16 + lg * 4 + r;
#pragma unroll
            for (int n = 0; n < 4; n++) {
                const int col = n0 + wc * 64 + n * 16 + li;
                float v = acc[m][n][r];
                if constexpr (EPI == 0) {
                    reinterpret_cast<unsigned short*>(out)[(size_t)row * N + col] = f2bf(v);
                } else if constexpr (EPI == 1) {
                    reinterpret_cast<float*>(out)[(size_t)row * N + col] =
                        v + resid[(size_t)row * N + col];
                } else if constexpr (EPI == 2) {
                    v += bias[col];
                    v = 0.5f * v * (1.0f + erff(v * 0.70710678118f));
                    reinterpret_cast<unsigned short*>(out)[(size_t)row * N + col] = f2bf(v);
                } else {
                    reinterpret_cast<float*>(out)[(size_t)row * N + col] =
                        v + bias[col] + resid[(size_t)row * N + col];
                }
            }
        }
    }
}

// ---------------- Flash attention (causal): Q,K,V bf16 [B*C][H*D] -> O bf16 [B*C][H*D] ----------------
// grid: (C/64, B*H). block: 256 (4 waves x 16 q-rows). KV tiles of 64 keys.
__global__ __launch_bounds__(256) void flash_kernel(
    const unsigned short* __restrict__ Q, const unsigned short* __restrict__ Kb,
    const unsigned short* __restrict__ Vb, unsigned short* __restrict__ O)
{
    constexpr int C = 2048, HD = 1024, D = 64;
    __shared__ unsigned short Kl[64][72];
    __shared__ unsigned short Vt[64][72];
    __shared__ unsigned short Pl[64][72];
    const int tid = threadIdx.x;
    const int lane = tid & 63, wid = tid >> 6;
    const int li = lane & 15, lg = lane >> 4;
    const int qt = blockIdx.x;
    const int bh = blockIdx.y;
    const int b = bh >> 4, h = bh & 15;
    const int q0 = qt * 64;
    const size_t base = ((size_t)b * C) * HD + (size_t)h * D;

    // Q fragments held in registers for the whole KV loop
    const int qrow = q0 + wid * 16 + li;
    bf16x8 qa0 = *reinterpret_cast<const bf16x8*>(&Q[base + (size_t)qrow * HD + lg * 8]);
    bf16x8 qa1 = *reinterpret_cast<const bf16x8*>(&Q[base + (size_t)qrow * HD + 32 + lg * 8]);

    f32x4 acc[4] = {};
    float mrun[4], lrun[4];
#pragma unroll
    for (int r = 0; r < 4; r++) { mrun[r] = -INFINITY; lrun[r] = 0.0f; }

    const int sr = tid >> 3;         // 0..31
    const int sc = (tid & 7) * 8;    // 0..56
    const int myrow0 = q0 + wid * 16 + lg * 4;

    for (int kt = 0; kt <= qt; kt++) {
        const int k0 = kt * 64;
        __syncthreads();
#pragma unroll
        for (int i = 0; i < 2; i++) {
            const int key = sr + 32 * i;
            const u16x8 kv = *reinterpret_cast<const u16x8*>(&Kb[base + (size_t)(k0 + key) * HD + sc]);
            *reinterpret_cast<u16x8*>(&Kl[key][sc]) = kv;
            const u16x8 vv = *reinterpret_cast<const u16x8*>(&Vb[base + (size_t)(k0 + key) * HD + sc]);
#pragma unroll
            for (int j = 0; j < 8; j++) Vt[sc + j][key] = vv[j];
        }
        __syncthreads();

        // S = Q K^T  (per wave: 16 q-rows x 64 keys)
        f32x4 s[4] = {};
#pragma unroll
        for (int n = 0; n < 4; n++) {
            const bf16x8 kb0 = *reinterpret_cast<const bf16x8*>(&Kl[n * 16 + li][lg * 8]);
            const bf16x8 kb1 = *reinterpret_cast<const bf16x8*>(&Kl[n * 16 + li][32 + lg * 8]);
            s[n] = __builtin_amdgcn_mfma_f32_16x16x32_bf16(qa0, kb0, s[n], 0, 0, 0);
            s[n] = __builtin_amdgcn_mfma_f32_16x16x32_bf16(qa1, kb1, s[n], 0, 0, 0);
        }

        // scale + causal mask + online softmax
        const bool diag = (kt == qt);
        float mt[4] = {-INFINITY, -INFINITY, -INFINITY, -INFINITY};
#pragma unroll
        for (int n = 0; n < 4; n++) {
            const int key = k0 + n * 16 + li;
#pragma unroll
            for (int r = 0; r < 4; r++) {
                float sv = s[n][r] * 0.125f;
                if (diag && key > myrow0 + r) sv = -INFINITY;
                s[n][r] = sv;
                mt[r] = fmaxf(mt[r], sv);
            }
        }
#pragma unroll
        for (int off = 1; off < 16; off <<= 1)
#pragma unroll
            for (int r = 0; r < 4; r++) mt[r] = fmaxf(mt[r], __shfl_xor(mt[r], off));

        float lp[4];
#pragma unroll
        for (int r = 0; r < 4; r++) {
            const float mn = fmaxf(mrun[r], mt[r]);
            const float al = __expf(mrun[r] - mn);
            mrun[r] = mn;
            lrun[r] *= al;
#pragma unroll
            for (int n = 0; n < 4; n++) acc[n][r] *= al;
            lp[r] = 0.0f;
        }
#pragma unroll
        for (int n = 0; n < 4; n++) {
#pragma unroll
            for (int r = 0; r < 4; r++) {
                const float pv = __expf(s[n][r] - mrun[r]);
                lp[r] += pv;
                Pl[wid * 16 + lg * 4 + r][n * 16 + li] = f2bf(pv);
            }
        }
#pragma unroll
        for (int off = 1; off < 16; off <<= 1)
#pragma unroll
            for (int r = 0; r < 4; r++) lp[r] += __shfl_xor(lp[r], off);
#pragma unroll
        for (int r = 0; r < 4; r++) lrun[r] += lp[r];

        __syncthreads();  // P visible; V/K stable until next stage

        // O += P V   (A = P from LDS, B = V^T from transposed stage)
#pragma unroll
        for (int ks = 0; ks < 2; ks++) {
            const bf16x8 pa = *reinterpret_cast<const bf16x8*>(&Pl[wid * 16 + li][ks * 32 + lg * 8]);
#pragma unroll
            for (int n = 0; n < 4; n++) {
                const bf16x8 vb = *reinterpret_cast<const bf16x8*>(&Vt[n * 16 + li][ks * 32 + lg * 8]);
                acc[n] = __builtin_amdgcn_mfma_f32_16x16x32_bf16(pa, vb, acc[n], 0, 0, 0);
            }
        }
    }

#pragma unroll
    for (int n = 0; n < 4; n++) {
#pragma unroll
        for (int r = 0; r < 4; r++) {
            const float v = acc[n][r] / lrun[r];
            const int row = myrow0 + r;
            O[base + (size_t)row * HD + n * 16 + li] = f2bf(v);
        }
    }
}

// ---------------- launch ----------------
extern "C" void kernel_launch(void* const* d_in, const int* in_sizes, int n_in,
                              void* d_out, int out_size, void* d_ws, size_t ws_size,
                              hipStream_t stream) {
    constexpr int B = 4, C = 2048, E = 1024, H = 16, FF = 4096;
    constexpr int M = B * C;  // 8192

    const float* x     = (const float*)d_in[0];
    const float* ln1_g = (const float*)d_in[1];
    const float* ln1_b = (const float*)d_in[2];
    const float* Wq    = (const float*)d_in[3];
    const float* Wk    = (const float*)d_in[4];
    const float* Wv    = (const float*)d_in[5];
    const float* Wo    = (const float*)d_in[6];
    const float* ln2_g = (const float*)d_in[7];
    const float* ln2_b = (const float*)d_in[8];
    const float* W1    = (const float*)d_in[9];
    const float* b1    = (const float*)d_in[10];
    const float* W2    = (const float*)d_in[11];
    const float* b2    = (const float*)d_in[12];

    char* p = (char*)d_ws;
    auto alloc = [&](size_t bytes) { void* r = (void*)p; p += (bytes + 255) & ~(size_t)255; return r; };
    unsigned short* WqT  = (unsigned short*)alloc((size_t)E * E * 2);
    unsigned short* WkT  = (unsigned short*)alloc((size_t)E * E * 2);
    unsigned short* WvT  = (unsigned short*)alloc((size_t)E * E * 2);
    unsigned short* WoT  = (unsigned short*)alloc((size_t)E * E * 2);
    unsigned short* W1T  = (unsigned short*)alloc((size_t)E * FF * 2);
    unsigned short* W2T  = (unsigned short*)alloc((size_t)FF * E * 2);
    unsigned short* hb   = (unsigned short*)alloc((size_t)M * E * 2);
    unsigned short* Qb   = (unsigned short*)alloc((size_t)M * E * 2);
    unsigned short* Kb   = (unsigned short*)alloc((size_t)M * E * 2);
    unsigned short* Vb   = (unsigned short*)alloc((size_t)M * E * 2);
    unsigned short* attn = (unsigned short*)alloc((size_t)M * E * 2);
    float*          x1   = (float*)alloc((size_t)M * E * 4);
    unsigned short* h2   = (unsigned short*)alloc((size_t)M * E * 2);
    unsigned short* ff   = (unsigned short*)alloc((size_t)M * FF * 2);

    // weight conversion / transpose
    convT_kernel<<<dim3(E / 32, E / 32), 256, 0, stream>>>(Wq, WqT, E, E);
    convT_kernel<<<dim3(E / 32, E / 32), 256, 0, stream>>>(Wk, WkT, E, E);
    convT_kernel<<<dim3(E / 32, E / 32), 256, 0, stream>>>(Wv, WvT, E, E);
    convT_kernel<<<dim3(E / 32, E / 32), 256, 0, stream>>>(Wo, WoT, E, E);
    convT_kernel<<<dim3(FF / 32, E / 32), 256, 0, stream>>>(W1, W1T, E, FF);
    convT_kernel<<<dim3(E / 32, FF / 32), 256, 0, stream>>>(W2, W2T, FF, E);

    // LN1
    ln_kernel<<<M, 256, 0, stream>>>(x, ln1_g, ln1_b, hb);

    // QKV projections
    gemm_kernel<0><<<dim3(E / 128, M / 128), 256, 0, stream>>>(hb, WqT, nullptr, nullptr, Qb, M, E, E);
    gemm_kernel<0><<<dim3(E / 128, M / 128), 256, 0, stream>>>(hb, WkT, nullptr, nullptr, Kb, M, E, E);
    gemm_kernel<0><<<dim3(E / 128, M / 128), 256, 0, stream>>>(hb, WvT, nullptr, nullptr, Vb, M, E, E);

    // attention
    flash_kernel<<<dim3(C / 64, B * H), 256, 0, stream>>>(Qb, Kb, Vb, attn);

    // output projection + residual
    gemm_kernel<1><<<dim3(E / 128, M / 128), 256, 0, stream>>>(attn, WoT, nullptr, x, x1, M, E, E);

    // LN2
    ln_kernel<<<M, 256, 0, stream>>>(x1, ln2_g, ln2_b, h2);

    // FFN
    gemm_kernel<2><<<dim3(FF / 128, M / 128), 256, 0, stream>>>(h2, W1T, b1, nullptr, ff, M, FF, E);
    gemm_kernel<3><<<dim3(E / 128, M / 128), 256, 0, stream>>>(ff, W2T, b2, x1, d_out, M, E, FF);
}

// Round 3
// 688.077 us; speedup vs baseline: 1.0001x; 1.0001x over previous
//
#include <hip/hip_runtime.h>

typedef __bf16 bf16x8 __attribute__((ext_vector_type(8)));
typedef float f32x4 __attribute__((ext_vector_type(4)));
typedef unsigned short u16x8 __attribute__((ext_vector_type(8)));
typedef unsigned short u16x4 __attribute__((ext_vector_type(4)));

__device__ __forceinline__ unsigned short f2bf(float f) {
    union { float f; unsigned int u; } a; a.f = f;
    unsigned int u = a.u;
    unsigned int r = (u + 0x7FFFu + ((u >> 16) & 1u)) >> 16;  // RNE
    return (unsigned short)r;
}

// ---------------- LayerNorm: fp32 in -> bf16 out (E=1024, one row per block) ----------------
__global__ __launch_bounds__(256) void ln_kernel(
    const float* __restrict__ x, const float* __restrict__ g,
    const float* __restrict__ b, unsigned short* __restrict__ out)
{
    const int row = blockIdx.x;
    const int tid = threadIdx.x;
    const float4 v = reinterpret_cast<const float4*>(x + (size_t)row * 1024)[tid];
    float s = v.x + v.y + v.z + v.w;
    float q = v.x * v.x + v.y * v.y + v.z * v.z + v.w * v.w;
#pragma unroll
    for (int off = 32; off >= 1; off >>= 1) {
        s += __shfl_xor(s, off);
        q += __shfl_xor(q, off);
    }
    __shared__ float ss[4], sq[4];
    const int wid = tid >> 6, lane = tid & 63;
    if (lane == 0) { ss[wid] = s; sq[wid] = q; }
    __syncthreads();
    s = ss[0] + ss[1] + ss[2] + ss[3];
    q = sq[0] + sq[1] + sq[2] + sq[3];
    const float mu = s * (1.0f / 1024.0f);
    const float var = q * (1.0f / 1024.0f) - mu * mu;
    const float rs = rsqrtf(var + 1e-5f);
    const float4 gv = reinterpret_cast<const float4*>(g)[tid];
    const float4 bv = reinterpret_cast<const float4*>(b)[tid];
    u16x4 o;
    o[0] = f2bf((v.x - mu) * rs * gv.x + bv.x);
    o[1] = f2bf((v.y - mu) * rs * gv.y + bv.y);
    o[2] = f2bf((v.z - mu) * rs * gv.z + bv.z);
    o[3] = f2bf((v.w - mu) * rs * gv.w + bv.w);
    reinterpret_cast<u16x4*>(out + (size_t)row * 1024)[tid] = o;
}

// ---------------- Weight convert + transpose: W[K][N] fp32 -> Wt[N][K] bf16 ----------------
__global__ __launch_bounds__(256) void convT_kernel(
    const float* __restrict__ W, unsigned short* __restrict__ Wt, int K, int N)
{
    __shared__ float t[32][33];
    const int n0 = blockIdx.x * 32, k0 = blockIdx.y * 32;
    const int tx = threadIdx.x & 31;
    const int ty = threadIdx.x >> 5;  // 0..7
#pragma unroll
    for (int i = 0; i < 4; i++)
        t[ty + 8 * i][tx] = W[(size_t)(k0 + ty + 8 * i) * N + (n0 + tx)];
    __syncthreads();
#pragma unroll
    for (int i = 0; i < 4; i++)
        Wt[(size_t)(n0 + ty + 8 * i) * K + (k0 + tx)] = f2bf(t[tx][ty + 8 * i]);
}

// ---------------- bf16 MFMA GEMM: C[M][N] = A[M][K] * Wt[N][K]^T, fused epilogues ----------------
// EPI 0: out bf16          EPI 1: out fp32 = acc + resid
// EPI 2: out bf16 = gelu(acc + bias)      EPI 3: out fp32 = acc + bias + resid
template <int EPI>
__global__ __launch_bounds__(256) void gemm_kernel(
    const unsigned short* __restrict__ A, const unsigned short* __restrict__ Bt,
    const float* __restrict__ bias, const float* __restrict__ resid,
    void* __restrict__ out, int M, int N, int K)
{
    __shared__ unsigned short Al[128][72];
    __shared__ unsigned short Bl[128][72];
    const int tid = threadIdx.x;
    const int lane = tid & 63, wid = tid >> 6;
    const int wr = wid >> 1, wc = wid & 1;      // 2x2 waves over 128x128
    const int li = lane & 15, lg = lane >> 4;
    const int m0 = blockIdx.y * 128, n0 = blockIdx.x * 128;
    const int sr = tid >> 3;                    // 0..31 staging row
    const int sc = (tid & 7) * 8;               // 0..56 staging col
    f32x4 acc[4][4] = {};

    for (int k0 = 0; k0 < K; k0 += 64) {
        __syncthreads();
#pragma unroll
        for (int i = 0; i < 4; i++) {
            const int r = sr + 32 * i;
            *reinterpret_cast<u16x8*>(&Al[r][sc]) =
                *reinterpret_cast<const u16x8*>(&A[(size_t)(m0 + r) * K + k0 + sc]);
            *reinterpret_cast<u16x8*>(&Bl[r][sc]) =
                *reinterpret_cast<const u16x8*>(&Bt[(size_t)(n0 + r) * K + k0 + sc]);
        }
        __syncthreads();
#pragma unroll
        for (int ks = 0; ks < 2; ks++) {
            const int kof = ks * 32 + lg * 8;
            bf16x8 af[4], bfr[4];
#pragma unroll
            for (int m = 0; m < 4; m++)
                af[m] = *reinterpret_cast<const bf16x8*>(&Al[wr * 64 + m * 16 + li][kof]);
#pragma unroll
            for (int n = 0; n < 4; n++)
                bfr[n] = *reinterpret_cast<const bf16x8*>(&Bl[wc * 64 + n * 16 + li][kof]);
#pragma unroll
            for (int m = 0; m < 4; m++)
#pragma unroll
                for (int n = 0; n < 4; n++)
                    acc[m][n] = __builtin_amdgcn_mfma_f32_16x16x32_bf16(af[m], bfr[n], acc[m][n], 0, 0, 0);
        }
    }

#pragma unroll
    for (int m = 0; m < 4; m++) {
#pragma unroll
        for (int r = 0; r < 4; r++) {
            const int row = m0 + wr * 64 + m * 16 + lg * 4 + r;
#pragma unroll
            for (int n = 0; n < 4; n++) {
                const int col = n0 + wc * 64 + n * 16 + li;
                float v = acc[m][n][r];
                if constexpr (EPI == 0) {
                    reinterpret_cast<unsigned short*>(out)[(size_t)row * N + col] = f2bf(v);
                } else if constexpr (EPI == 1) {
                    reinterpret_cast<float*>(out)[(size_t)row * N + col] =
                        v + resid[(size_t)row * N + col];
                } else if constexpr (EPI == 2) {
                    v += bias[col];
                    v = 0.5f * v * (1.0f + erff(v * 0.70710678118f));
                    reinterpret_cast<unsigned short*>(out)[(size_t)row * N + col] = f2bf(v);
                } else {
                    reinterpret_cast<float*>(out)[(size_t)row * N + col] =
                        v + bias[col] + resid[(size_t)row * N + col];
                }
            }
        }
    }
}

// ---------------- Flash attention (causal): Q,K,V bf16 [B*C][H*D] -> O bf16 [B*C][H*D] ----------------
// grid: (C/64, B*H). block: 256 (4 waves x 16 q-rows). KV tiles of 64 keys.
__global__ __launch_bounds__(256) void flash_kernel(
    const unsigned short* __restrict__ Q, const unsigned short* __restrict__ Kb,
    const unsigned short* __restrict__ Vb, unsigned short* __restrict__ O)
{
    constexpr int C = 2048, HD = 1024, D = 64;
    __shared__ unsigned short Kl[64][72];
    __shared__ unsigned short Vt[64][72];
    __shared__ unsigned short Pl[64][72];
    const int tid = threadIdx.x;
    const int lane = tid & 63, wid = tid >> 6;
    const int li = lane & 15, lg = lane >> 4;
    const int qt = blockIdx.x;
    const int bh = blockIdx.y;
    const int b = bh >> 4, h = bh & 15;
    const int q0 = qt * 64;
    const size_t base = ((size_t)b * C) * HD + (size_t)h * D;

    // Q fragments held in registers for the whole KV loop
    const int qrow = q0 + wid * 16 + li;
    bf16x8 qa0 = *reinterpret_cast<const bf16x8*>(&Q[base + (size_t)qrow * HD + lg * 8]);
    bf16x8 qa1 = *reinterpret_cast<const bf16x8*>(&Q[base + (size_t)qrow * HD + 32 + lg * 8]);

    f32x4 acc[4] = {};
    float mrun[4], lrun[4];
#pragma unroll
    for (int r = 0; r < 4; r++) { mrun[r] = -INFINITY; lrun[r] = 0.0f; }

    const int sr = tid >> 3;         // 0..31
    const int sc = (tid & 7) * 8;    // 0..56
    const int myrow0 = q0 + wid * 16 + lg * 4;

    for (int kt = 0; kt <= qt; kt++) {
        const int k0 = kt * 64;
        __syncthreads();
#pragma unroll
        for (int i = 0; i < 2; i++) {
            const int key = sr + 32 * i;
            const u16x8 kv = *reinterpret_cast<const u16x8*>(&Kb[base + (size_t)(k0 + key) * HD + sc]);
            *reinterpret_cast<u16x8*>(&Kl[key][sc]) = kv;
            const u16x8 vv = *reinterpret_cast<const u16x8*>(&Vb[base + (size_t)(k0 + key) * HD + sc]);
#pragma unroll
            for (int j = 0; j < 8; j++) Vt[sc + j][key] = vv[j];
        }
        __syncthreads();

        // S = Q K^T  (per wave: 16 q-rows x 64 keys)
        f32x4 s[4] = {};
#pragma unroll
        for (int n = 0; n < 4; n++) {
            const bf16x8 kb0 = *reinterpret_cast<const bf16x8*>(&Kl[n * 16 + li][lg * 8]);
            const bf16x8 kb1 = *reinterpret_cast<const bf16x8*>(&Kl[n * 16 + li][32 + lg * 8]);
            s[n] = __builtin_amdgcn_mfma_f32_16x16x32_bf16(qa0, kb0, s[n], 0, 0, 0);
            s[n] = __builtin_amdgcn_mfma_f32_16x16x32_bf16(qa1, kb1, s[n], 0, 0, 0);
        }

        // scale + causal mask + online softmax
        const bool diag = (kt == qt);
        float mt[4] = {-INFINITY, -INFINITY, -INFINITY, -INFINITY};
#pragma unroll
        for (int n = 0; n < 4; n++) {
            const int key = k0 + n * 16 + li;
#pragma unroll
            for (int r = 0; r < 4; r++) {
                float sv = s[n][r] * 0.125f;
                if (diag && key > myrow0 + r) sv = -INFINITY;
                s[n][r] = sv;
                mt[r] = fmaxf(mt[r], sv);
            }
        }
#pragma unroll
        for (int off = 1; off < 16; off <<= 1)
#pragma unroll
            for (int r = 0; r < 4; r++) mt[r] = fmaxf(mt[r], __shfl_xor(mt[r], off));

        float lp[4];
#pragma unroll
        for (int r = 0; r < 4; r++) {
            const float mn = fmaxf(mrun[r], mt[r]);
            const float al = __expf(mrun[r] - mn);
            mrun[r] = mn;
            lrun[r] *= al;
#pragma unroll
            for (int n = 0; n < 4; n++) acc[n][r] *= al;
            lp[r] = 0.0f;
        }
#pragma unroll
        for (int n = 0; n < 4; n++) {
#pragma unroll
            for (int r = 0; r < 4; r++) {
                const float pv = __expf(s[n][r] - mrun[r]);
                lp[r] += pv;
                Pl[wid * 16 + lg * 4 + r][n * 16 + li] = f2bf(pv);
            }
        }
#pragma unroll
        for (int off = 1; off < 16; off <<= 1)
#pragma unroll
            for (int r = 0; r < 4; r++) lp[r] += __shfl_xor(lp[r], off);
#pragma unroll
        for (int r = 0; r < 4; r++) lrun[r] += lp[r];

        __syncthreads();  // P visible; V/K stable until next stage

        // O += P V   (A = P from LDS, B = V^T from transposed stage)
#pragma unroll
        for (int ks = 0; ks < 2; ks++) {
            const bf16x8 pa = *reinterpret_cast<const bf16x8*>(&Pl[wid * 16 + li][ks * 32 + lg * 8]);
#pragma unroll
            for (int n = 0; n < 4; n++) {
                const bf16x8 vb = *reinterpret_cast<const bf16x8*>(&Vt[n * 16 + li][ks * 32 + lg * 8]);
                acc[n] = __builtin_amdgcn_mfma_f32_16x16x32_bf16(pa, vb, acc[n], 0, 0, 0);
            }
        }
    }

#pragma unroll
    for (int n = 0; n < 4; n++) {
#pragma unroll
        for (int r = 0; r < 4; r++) {
            const float v = acc[n][r] / lrun[r];
            const int row = myrow0 + r;
            O[base + (size_t)row * HD + n * 16 + li] = f2bf(v);
        }
    }
}

// ---------------- launch ----------------
extern "C" void kernel_launch(void* const* d_in, const int* in_sizes, int n_in,
                              void* d_out, int out_size, void* d_ws, size_t ws_size,
                              hipStream_t stream) {
    constexpr int B = 4, C = 2048, E = 1024, H = 16, FF = 4096;
    constexpr int M = B * C;  // 8192

    const float* x     = (const float*)d_in[0];
    const float* ln1_g = (const float*)d_in[1];
    const float* ln1_b = (const float*)d_in[2];
    const float* Wq    = (const float*)d_in[3];
    const float* Wk    = (const float*)d_in[4];
    const float* Wv    = (const float*)d_in[5];
    const float* Wo    = (const float*)d_in[6];
    const float* ln2_g = (const float*)d_in[7];
    const float* ln2_b = (const float*)d_in[8];
    const float* W1    = (const float*)d_in[9];
    const float* b1    = (const float*)d_in[10];
    const float* W2    = (const float*)d_in[11];
    const float* b2    = (const float*)d_in[12];

    char* p = (char*)d_ws;
    auto alloc = [&](size_t bytes) { void* r = (void*)p; p += (bytes + 255) & ~(size_t)255; return r; };
    unsigned short* WqT  = (unsigned short*)alloc((size_t)E * E * 2);
    unsigned short* WkT  = (unsigned short*)alloc((size_t)E * E * 2);
    unsigned short* WvT  = (unsigned short*)alloc((size_t)E * E * 2);
    unsigned short* WoT  = (unsigned short*)alloc((size_t)E * E * 2);
    unsigned short* W1T  = (unsigned short*)alloc((size_t)E * FF * 2);
    unsigned short* W2T  = (unsigned short*)alloc((size_t)FF * E * 2);
    unsigned short* hb   = (unsigned short*)alloc((size_t)M * E * 2);
    unsigned short* Qb   = (unsigned short*)alloc((size_t)M * E * 2);
    unsigned short* Kb   = (unsigned short*)alloc((size_t)M * E * 2);
    unsigned short* Vb   = (unsigned short*)alloc((size_t)M * E * 2);
    unsigned short* attn = (unsigned short*)alloc((size_t)M * E * 2);
    float*          x1   = (float*)alloc((size_t)M * E * 4);
    unsigned short* h2   = (unsigned short*)alloc((size_t)M * E * 2);
    unsigned short* ff   = (unsigned short*)alloc((size_t)M * FF * 2);

    // weight conversion / transpose
    convT_kernel<<<dim3(E / 32, E / 32), 256, 0, stream>>>(Wq, WqT, E, E);
    convT_kernel<<<dim3(E / 32, E / 32), 256, 0, stream>>>(Wk, WkT, E, E);
    convT_kernel<<<dim3(E / 32, E / 32), 256, 0, stream>>>(Wv, WvT, E, E);
    convT_kernel<<<dim3(E / 32, E / 32), 256, 0, stream>>>(Wo, WoT, E, E);
    convT_kernel<<<dim3(FF / 32, E / 32), 256, 0, stream>>>(W1, W1T, E, FF);
    convT_kernel<<<dim3(E / 32, FF / 32), 256, 0, stream>>>(W2, W2T, FF, E);

    // LN1
    ln_kernel<<<M, 256, 0, stream>>>(x, ln1_g, ln1_b, hb);

    // QKV projections
    gemm_kernel<0><<<dim3(E / 128, M / 128), 256, 0, stream>>>(hb, WqT, nullptr, nullptr, Qb, M, E, E);
    gemm_kernel<0><<<dim3(E / 128, M / 128), 256, 0, stream>>>(hb, WkT, nullptr, nullptr, Kb, M, E, E);
    gemm_kernel<0><<<dim3(E / 128, M / 128), 256, 0, stream>>>(hb, WvT, nullptr, nullptr, Vb, M, E, E);

    // attention
    flash_kernel<<<dim3(C / 64, B * H), 256, 0, stream>>>(Qb, Kb, Vb, attn);

    // output projection + residual
    gemm_kernel<1><<<dim3(E / 128, M / 128), 256, 0, stream>>>(attn, WoT, nullptr, x, x1, M, E, E);

    // LN2
    ln_kernel<<<M, 256, 0, stream>>>(x1, ln2_g, ln2_b, h2);

    // FFN
    gemm_kernel<2><<<dim3(FF / 128, M / 128), 256, 0, stream>>>(h2, W1T, b1, nullptr, ff, M, FF, E);
    gemm_kernel<3><<<dim3(E / 128, M / 128), 256, 0, stream>>>(ff, W2T, b2, x1, d_out, M, E, FF);
}

// Round 4
// 442.854 us; speedup vs baseline: 1.5538x; 1.5537x over previous
//
#include <hip/hip_runtime.h>

typedef __bf16 bf16x8 __attribute__((ext_vector_type(8)));
typedef float f32x4 __attribute__((ext_vector_type(4)));
typedef unsigned short u16x8 __attribute__((ext_vector_type(8)));
typedef unsigned short u16x4 __attribute__((ext_vector_type(4)));

__device__ __forceinline__ unsigned short f2bf(float f) {
    return __builtin_bit_cast(unsigned short, (__bf16)f);  // v_cvt_pk_bf16_f32, RNE
}

__device__ __forceinline__ void gload_lds16(const unsigned short* g, unsigned short* l) {
    __builtin_amdgcn_global_load_lds(
        (const __attribute__((address_space(1))) unsigned int*)g,
        (__attribute__((address_space(3))) unsigned int*)l, 16, 0, 0);
}

// ---------------- LayerNorm: fp32 in -> bf16 out (E=1024, one row per block) ----------------
__global__ __launch_bounds__(256) void ln_kernel(
    const float* __restrict__ x, const float* __restrict__ g,
    const float* __restrict__ b, unsigned short* __restrict__ out)
{
    const int row = blockIdx.x;
    const int tid = threadIdx.x;
    const float4 v = reinterpret_cast<const float4*>(x + (size_t)row * 1024)[tid];
    float s = v.x + v.y + v.z + v.w;
    float q = v.x * v.x + v.y * v.y + v.z * v.z + v.w * v.w;
#pragma unroll
    for (int off = 32; off >= 1; off >>= 1) {
        s += __shfl_xor(s, off);
        q += __shfl_xor(q, off);
    }
    __shared__ float ss[4], sq[4];
    const int wid = tid >> 6, lane = tid & 63;
    if (lane == 0) { ss[wid] = s; sq[wid] = q; }
    __syncthreads();
    s = ss[0] + ss[1] + ss[2] + ss[3];
    q = sq[0] + sq[1] + sq[2] + sq[3];
    const float mu = s * (1.0f / 1024.0f);
    const float var = q * (1.0f / 1024.0f) - mu * mu;
    const float rs = rsqrtf(var + 1e-5f);
    const float4 gv = reinterpret_cast<const float4*>(g)[tid];
    const float4 bv = reinterpret_cast<const float4*>(b)[tid];
    u16x4 o;
    o[0] = f2bf((v.x - mu) * rs * gv.x + bv.x);
    o[1] = f2bf((v.y - mu) * rs * gv.y + bv.y);
    o[2] = f2bf((v.z - mu) * rs * gv.z + bv.z);
    o[3] = f2bf((v.w - mu) * rs * gv.w + bv.w);
    reinterpret_cast<u16x4*>(out + (size_t)row * 1024)[tid] = o;
}

// ---------------- Weight convert + transpose: W[K][N] fp32 -> Wt[N][K] bf16 ----------------
__global__ __launch_bounds__(256) void convT_kernel(
    const float* __restrict__ W, unsigned short* __restrict__ Wt, int K, int N)
{
    __shared__ float t[32][33];
    const int n0 = blockIdx.x * 32, k0 = blockIdx.y * 32;
    const int tx = threadIdx.x & 31;
    const int ty = threadIdx.x >> 5;  // 0..7
#pragma unroll
    for (int i = 0; i < 4; i++)
        t[ty + 8 * i][tx] = W[(size_t)(k0 + ty + 8 * i) * N + (n0 + tx)];
    __syncthreads();
#pragma unroll
    for (int i = 0; i < 4; i++)
        Wt[(size_t)(n0 + ty + 8 * i) * K + (k0 + tx)] = f2bf(t[tx][ty + 8 * i]);
}

// ---------------- bf16 MFMA GEMM (m97 structure): C = A[M][K] * Bt[N][K]^T ----------------
// LDS linear [128][64], global_load_lds dwordx4, both-sides chunk-XOR swizzle (T21).
// EPI 0: out bf16          EPI 1: out fp32 = acc + resid
// EPI 2: out bf16 = gelu_tanh(acc + bias)   EPI 3: out fp32 = acc + bias + resid
template <int EPI>
__global__ __launch_bounds__(256) void gemm_kernel(
    const unsigned short* __restrict__ A, const unsigned short* __restrict__ Bt,
    const float* __restrict__ bias, const float* __restrict__ resid,
    void* __restrict__ out, int M, int N, int K)
{
    __shared__ unsigned short Al[128][64];
    __shared__ unsigned short Bl[128][64];
    const int tid = threadIdx.x;
    const int lane = tid & 63, wid = tid >> 6;
    const int wr = wid >> 1, wc = wid & 1;      // 2x2 waves over 128x128
    const int li = lane & 15, lg = lane >> 4;
    const int m0 = blockIdx.y * 128, n0 = blockIdx.x * 128;
    // staging: wave wid stages rows [wid*32, wid*32+32), 4 instrs x 8 rows x 64 shorts.
    // LDS chunk (row, c) holds global chunk c ^ (row&7)  ->  source pre-swizzled.
    const int srow = lane >> 3;                          // 0..7
    const int schunk = ((lane & 7) ^ srow) * 8;          // swizzled source col (shorts)
    const unsigned short* Asrc = A + (size_t)(m0 + wid * 32 + srow) * K + schunk;
    const unsigned short* Bsrc = Bt + (size_t)(n0 + wid * 32 + srow) * K + schunk;
    f32x4 acc[4][4] = {};

    for (int k0 = 0; k0 < K; k0 += 64) {
        __syncthreads();
#pragma unroll
        for (int i = 0; i < 4; i++) {
            gload_lds16(Asrc + k0 + (size_t)i * 8 * K, &Al[wid * 32 + i * 8][0]);
            gload_lds16(Bsrc + k0 + (size_t)i * 8 * K, &Bl[wid * 32 + i * 8][0]);
        }
        __syncthreads();
#pragma unroll
        for (int ks = 0; ks < 2; ks++) {
            bf16x8 af[4], bfr[4];
#pragma unroll
            for (int m = 0; m < 4; m++)
                af[m] = *reinterpret_cast<const bf16x8*>(
                    &Al[wr * 64 + m * 16 + li][((ks * 4 + lg) ^ (li & 7)) * 8]);
#pragma unroll
            for (int n = 0; n < 4; n++)
                bfr[n] = *reinterpret_cast<const bf16x8*>(
                    &Bl[wc * 64 + n * 16 + li][((ks * 4 + lg) ^ (li & 7)) * 8]);
#pragma unroll
            for (int m = 0; m < 4; m++)
#pragma unroll
                for (int n = 0; n < 4; n++)
                    acc[m][n] = __builtin_amdgcn_mfma_f32_16x16x32_bf16(af[m], bfr[n], acc[m][n], 0, 0, 0);
        }
    }

#pragma unroll
    for (int m = 0; m < 4; m++) {
#pragma unroll
        for (int r = 0; r < 4; r++) {
            const int row = m0 + wr * 64 + m * 16 + lg * 4 + r;
#pragma unroll
            for (int n = 0; n < 4; n++) {
                const int col = n0 + wc * 64 + n * 16 + li;
                float v = acc[m][n][r];
                if constexpr (EPI == 0) {
                    reinterpret_cast<unsigned short*>(out)[(size_t)row * N + col] = f2bf(v);
                } else if constexpr (EPI == 1) {
                    reinterpret_cast<float*>(out)[(size_t)row * N + col] =
                        v + resid[(size_t)row * N + col];
                } else if constexpr (EPI == 2) {
                    v += bias[col];
                    // gelu(x) ~= x * sigmoid(1.5957691 * (x + 0.044715 x^3))  (tanh form)
                    float a2 = 1.5957691216f * (v + 0.044715f * v * v * v);
                    a2 = fminf(a2, 80.0f);
                    const float t = __expf(a2);
                    v = v * t * __builtin_amdgcn_rcpf(t + 1.0f);
                    reinterpret_cast<unsigned short*>(out)[(size_t)row * N + col] = f2bf(v);
                } else {
                    reinterpret_cast<float*>(out)[(size_t)row * N + col] =
                        v + bias[col] + resid[(size_t)row * N + col];
                }
            }
        }
    }
}

// ---------------- Flash attention (causal), balanced q-tile pairs ----------------
// flat grid 1024: bh = id&63 (XCD-grouped), pair = id>>6 in 0..15 -> qt in {pair, 31-pair}.
// block: 256 (4 waves x 16 q-rows), KV tiles of 64.
__global__ __launch_bounds__(256) void flash_kernel(
    const unsigned short* __restrict__ Q, const unsigned short* __restrict__ Kb,
    const unsigned short* __restrict__ Vb, unsigned short* __restrict__ O)
{
    constexpr int C = 2048, HD = 1024, NT = C / 64;
    __shared__ unsigned short Kl[64][64];   // linear, gload_lds + source chunk-swizzle
    __shared__ unsigned short Vt[64][72];   // V^T [d][key], 16B-chunk XOR swizzle on key
    __shared__ unsigned short Pl[64][72];   // P [q][key], wave-private rows
    const int tid = threadIdx.x;
    const int lane = tid & 63, wid = tid >> 6;
    const int li = lane & 15, lg = lane >> 4;
    const int flat = blockIdx.x;
    const int bh = flat & 63;                // blocks of one head land on one XCD
    const int pair = flat >> 6;              // 0..15
    const int b = bh >> 4, h = bh & 15;
    const size_t base = ((size_t)b * C) * HD + (size_t)h * 64;

    const int srow = lane >> 3;                      // K staging
    const int schunk = ((lane & 7) ^ srow) * 8;
    const int vx = tid & 7;                          // V staging: rows vx*8..vx*8+7

    const u16x8 onesu = {0x3F80, 0x3F80, 0x3F80, 0x3F80, 0x3F80, 0x3F80, 0x3F80, 0x3F80};
    const bf16x8 ones = __builtin_bit_cast(bf16x8, onesu);

    for (int half = 0; half < 2; half++) {
        const int qt = half == 0 ? pair : (NT - 1 - pair);
        const int q0 = qt * 64;
        const int qrow = q0 + wid * 16 + li;
        const bf16x8 qa0 = *reinterpret_cast<const bf16x8*>(&Q[base + (size_t)qrow * HD + lg * 8]);
        const bf16x8 qa1 = *reinterpret_cast<const bf16x8*>(&Q[base + (size_t)qrow * HD + 32 + lg * 8]);
        const int myrow0 = q0 + wid * 16 + lg * 4;

        f32x4 acc[4] = {};
        f32x4 accl = {};
        float mrun[4];
#pragma unroll
        for (int r = 0; r < 4; r++) mrun[r] = -INFINITY;

        for (int kt = 0; kt <= qt; kt++) {
            const int k0 = kt * 64;
            __syncthreads();  // all waves done reading Kl/Vt of previous tile
            // K: async global->LDS, wave wid rows [wid*16, wid*16+16)
#pragma unroll
            for (int i = 0; i < 2; i++)
                gload_lds16(&Kb[base + (size_t)(k0 + wid * 16 + i * 8 + srow) * HD + schunk],
                            &Kl[wid * 16 + i * 8][0]);
            // V: load row-major, store transposed with 16B-chunk XOR swizzle
#pragma unroll
            for (int i = 0; i < 2; i++) {
                const int key = (tid >> 3) + 32 * i;
                const u16x8 vv = *reinterpret_cast<const u16x8*>(
                    &Vb[base + (size_t)(k0 + key) * HD + vx * 8]);
                const int colc = (((key >> 3) ^ vx) << 3) | (key & 7);
#pragma unroll
                for (int j = 0; j < 8; j++) Vt[vx * 8 + j][colc] = vv[j];
            }
            __syncthreads();  // staging complete

            // S = Q K^T
            f32x4 s[4] = {};
#pragma unroll
            for (int n = 0; n < 4; n++) {
                const int row = n * 16 + li;
                const bf16x8 kb0 = *reinterpret_cast<const bf16x8*>(&Kl[row][(lg ^ (li & 7)) * 8]);
                const bf16x8 kb1 = *reinterpret_cast<const bf16x8*>(&Kl[row][((4 + lg) ^ (li & 7)) * 8]);
                s[n] = __builtin_amdgcn_mfma_f32_16x16x32_bf16(qa0, kb0, s[n], 0, 0, 0);
                s[n] = __builtin_amdgcn_mfma_f32_16x16x32_bf16(qa1, kb1, s[n], 0, 0, 0);
            }

            // scale + causal mask + per-row max
            const bool diag = (kt == qt);
            float mt[4] = {-INFINITY, -INFINITY, -INFINITY, -INFINITY};
#pragma unroll
            for (int n = 0; n < 4; n++) {
                const int key = k0 + n * 16 + li;
#pragma unroll
                for (int r = 0; r < 4; r++) {
                    float sv = s[n][r] * 0.125f;
                    if (diag && key > myrow0 + r) sv = -INFINITY;
                    s[n][r] = sv;
                    mt[r] = fmaxf(mt[r], sv);
                }
            }
#pragma unroll
            for (int off = 1; off < 16; off <<= 1)
#pragma unroll
                for (int r = 0; r < 4; r++) mt[r] = fmaxf(mt[r], __shfl_xor(mt[r], off));

            float al[4];
#pragma unroll
            for (int r = 0; r < 4; r++) {
                const float mn = fmaxf(mrun[r], mt[r]);
                al[r] = __expf(mrun[r] - mn);
                mrun[r] = mn;
            }
#pragma unroll
            for (int n = 0; n < 4; n++)
#pragma unroll
                for (int r = 0; r < 4; r++) acc[n][r] *= al[r];
#pragma unroll
            for (int r = 0; r < 4; r++) accl[r] *= al[r];

            // P = exp(S - m), bf16, stored to wave-private Pl rows (no barrier needed)
#pragma unroll
            for (int n = 0; n < 4; n++)
#pragma unroll
                for (int r = 0; r < 4; r++)
                    Pl[wid * 16 + lg * 4 + r][n * 16 + li] = f2bf(__expf(s[n][r] - mrun[r]));

            // O += P V ; row-sums via ones-column MFMA (replaces shuffle tree)
#pragma unroll
            for (int ks = 0; ks < 2; ks++) {
                const bf16x8 pa = *reinterpret_cast<const bf16x8*>(
                    &Pl[wid * 16 + li][ks * 32 + lg * 8]);
#pragma unroll
                for (int n = 0; n < 4; n++) {
                    const int row = n * 16 + li;
                    const int x = (n << 1) | (li >> 3);  // row>>3
                    const bf16x8 vb = *reinterpret_cast<const bf16x8*>(
                        &Vt[row][((ks * 4 + lg) ^ x) << 3]);
                    acc[n] = __builtin_amdgcn_mfma_f32_16x16x32_bf16(pa, vb, acc[n], 0, 0, 0);
                }
                accl = __builtin_amdgcn_mfma_f32_16x16x32_bf16(pa, ones, accl, 0, 0, 0);
            }
        }

        // epilogue: O / l
#pragma unroll
        for (int r = 0; r < 4; r++) {
            const float inv = 1.0f / accl[r];
            const int row = myrow0 + r;
#pragma unroll
            for (int n = 0; n < 4; n++)
                O[base + (size_t)row * HD + n * 16 + li] = f2bf(acc[n][r] * inv);
        }
    }
}

// ---------------- launch ----------------
extern "C" void kernel_launch(void* const* d_in, const int* in_sizes, int n_in,
                              void* d_out, int out_size, void* d_ws, size_t ws_size,
                              hipStream_t stream) {
    constexpr int B = 4, C = 2048, E = 1024, H = 16, FF = 4096;
    constexpr int M = B * C;  // 8192

    const float* x     = (const float*)d_in[0];
    const float* ln1_g = (const float*)d_in[1];
    const float* ln1_b = (const float*)d_in[2];
    const float* Wq    = (const float*)d_in[3];
    const float* Wk    = (const float*)d_in[4];
    const float* Wv    = (const float*)d_in[5];
    const float* Wo    = (const float*)d_in[6];
    const float* ln2_g = (const float*)d_in[7];
    const float* ln2_b = (const float*)d_in[8];
    const float* W1    = (const float*)d_in[9];
    const float* b1    = (const float*)d_in[10];
    const float* W2    = (const float*)d_in[11];
    const float* b2    = (const float*)d_in[12];

    char* p = (char*)d_ws;
    auto alloc = [&](size_t bytes) { void* r = (void*)p; p += (bytes + 255) & ~(size_t)255; return r; };
    unsigned short* WqT  = (unsigned short*)alloc((size_t)E * E * 2);
    unsigned short* WkT  = (unsigned short*)alloc((size_t)E * E * 2);
    unsigned short* WvT  = (unsigned short*)alloc((size_t)E * E * 2);
    unsigned short* WoT  = (unsigned short*)alloc((size_t)E * E * 2);
    unsigned short* W1T  = (unsigned short*)alloc((size_t)E * FF * 2);
    unsigned short* W2T  = (unsigned short*)alloc((size_t)FF * E * 2);
    unsigned short* hb   = (unsigned short*)alloc((size_t)M * E * 2);
    unsigned short* Qb   = (unsigned short*)alloc((size_t)M * E * 2);
    unsigned short* Kb   = (unsigned short*)alloc((size_t)M * E * 2);
    unsigned short* Vb   = (unsigned short*)alloc((size_t)M * E * 2);
    unsigned short* attn = (unsigned short*)alloc((size_t)M * E * 2);
    float*          x1   = (float*)alloc((size_t)M * E * 4);
    unsigned short* h2   = (unsigned short*)alloc((size_t)M * E * 2);
    unsigned short* ff   = (unsigned short*)alloc((size_t)M * FF * 2);

    // weight conversion / transpose
    convT_kernel<<<dim3(E / 32, E / 32), 256, 0, stream>>>(Wq, WqT, E, E);
    convT_kernel<<<dim3(E / 32, E / 32), 256, 0, stream>>>(Wk, WkT, E, E);
    convT_kernel<<<dim3(E / 32, E / 32), 256, 0, stream>>>(Wv, WvT, E, E);
    convT_kernel<<<dim3(E / 32, E / 32), 256, 0, stream>>>(Wo, WoT, E, E);
    convT_kernel<<<dim3(FF / 32, E / 32), 256, 0, stream>>>(W1, W1T, E, FF);
    convT_kernel<<<dim3(E / 32, FF / 32), 256, 0, stream>>>(W2, W2T, FF, E);

    // LN1
    ln_kernel<<<M, 256, 0, stream>>>(x, ln1_g, ln1_b, hb);

    // QKV projections
    gemm_kernel<0><<<dim3(E / 128, M / 128), 256, 0, stream>>>(hb, WqT, nullptr, nullptr, Qb, M, E, E);
    gemm_kernel<0><<<dim3(E / 128, M / 128), 256, 0, stream>>>(hb, WkT, nullptr, nullptr, Kb, M, E, E);
    gemm_kernel<0><<<dim3(E / 128, M / 128), 256, 0, stream>>>(hb, WvT, nullptr, nullptr, Vb, M, E, E);

    // attention (balanced pairs, XCD-grouped heads)
    flash_kernel<<<dim3(1024), 256, 0, stream>>>(Qb, Kb, Vb, attn);

    // output projection + residual
    gemm_kernel<1><<<dim3(E / 128, M / 128), 256, 0, stream>>>(attn, WoT, nullptr, x, x1, M, E, E);

    // LN2
    ln_kernel<<<M, 256, 0, stream>>>(x1, ln2_g, ln2_b, h2);

    // FFN
    gemm_kernel<2><<<dim3(FF / 128, M / 128), 256, 0, stream>>>(h2, W1T, b1, nullptr, ff, M, FF, E);
    gemm_kernel<3><<<dim3(E / 128, M / 128), 256, 0, stream>>>(ff, W2T, b2, x1, d_out, M, E, FF);
}

// Round 5
// 386.313 us; speedup vs baseline: 1.7813x; 1.1464x over previous
//
#include <hip/hip_runtime.h>

typedef __bf16 bf16x8 __attribute__((ext_vector_type(8)));
typedef float f32x4 __attribute__((ext_vector_type(4)));
typedef unsigned short u16x8 __attribute__((ext_vector_type(8)));
typedef unsigned short u16x4 __attribute__((ext_vector_type(4)));

__device__ __forceinline__ unsigned short f2bf(float f) {
    return __builtin_bit_cast(unsigned short, (__bf16)f);  // v_cvt RNE
}

__device__ __forceinline__ float fexp2(float x) {
#if __has_builtin(__builtin_amdgcn_exp2f)
    return __builtin_amdgcn_exp2f(x);
#else
    float r; asm("v_exp_f32 %0, %1\n\ts_nop 1" : "=v"(r) : "v"(x)); return r;
#endif
}

__device__ __forceinline__ void gload_lds16(const unsigned short* g, unsigned short* l) {
    __builtin_amdgcn_global_load_lds(
        (const __attribute__((address_space(1))) unsigned int*)g,
        (__attribute__((address_space(3))) unsigned int*)l, 16, 0, 0);
}

// Q pre-scale: 1/sqrt(64) * log2(e), folded into the QKV GEMM epilogue (Q cols only)
#define QSCALE 0.18033688011112042f

// ---------------- LayerNorm: fp32 in -> bf16 out (E=1024, one row per block) ----------------
__global__ __launch_bounds__(256) void ln_kernel(
    const float* __restrict__ x, const float* __restrict__ g,
    const float* __restrict__ b, unsigned short* __restrict__ out)
{
    const int row = blockIdx.x;
    const int tid = threadIdx.x;
    const float4 v = reinterpret_cast<const float4*>(x + (size_t)row * 1024)[tid];
    float s = v.x + v.y + v.z + v.w;
    float q = v.x * v.x + v.y * v.y + v.z * v.z + v.w * v.w;
#pragma unroll
    for (int off = 32; off >= 1; off >>= 1) {
        s += __shfl_xor(s, off);
        q += __shfl_xor(q, off);
    }
    __shared__ float ss[4], sq[4];
    const int wid = tid >> 6, lane = tid & 63;
    if (lane == 0) { ss[wid] = s; sq[wid] = q; }
    __syncthreads();
    s = ss[0] + ss[1] + ss[2] + ss[3];
    q = sq[0] + sq[1] + sq[2] + sq[3];
    const float mu = s * (1.0f / 1024.0f);
    const float var = q * (1.0f / 1024.0f) - mu * mu;
    const float rs = rsqrtf(var + 1e-5f);
    const float4 gv = reinterpret_cast<const float4*>(g)[tid];
    const float4 bv = reinterpret_cast<const float4*>(b)[tid];
    u16x4 o;
    o[0] = f2bf((v.x - mu) * rs * gv.x + bv.x);
    o[1] = f2bf((v.y - mu) * rs * gv.y + bv.y);
    o[2] = f2bf((v.z - mu) * rs * gv.z + bv.z);
    o[3] = f2bf((v.w - mu) * rs * gv.w + bv.w);
    reinterpret_cast<u16x4*>(out + (size_t)row * 1024)[tid] = o;
}

// ---------------- Weight convert + transpose: W[K][N] fp32 -> Wt[N][K] bf16 ----------------
__global__ __launch_bounds__(256) void convT_kernel(
    const float* __restrict__ W, unsigned short* __restrict__ Wt, int K, int N)
{
    __shared__ float t[32][33];
    const int n0 = blockIdx.x * 32, k0 = blockIdx.y * 32;
    const int tx = threadIdx.x & 31;
    const int ty = threadIdx.x >> 5;
#pragma unroll
    for (int i = 0; i < 4; i++)
        t[ty + 8 * i][tx] = W[(size_t)(k0 + ty + 8 * i) * N + (n0 + tx)];
    __syncthreads();
#pragma unroll
    for (int i = 0; i < 4; i++)
        Wt[(size_t)(n0 + ty + 8 * i) * K + (k0 + tx)] = f2bf(t[tx][ty + 8 * i]);
}

// 4 square E x E transposes in one dispatch (z picks the matrix; dsts contiguous)
__global__ __launch_bounds__(256) void convT4_kernel(
    const float* __restrict__ A0, const float* __restrict__ A1,
    const float* __restrict__ A2, const float* __restrict__ A3,
    unsigned short* __restrict__ Wt)
{
    constexpr int E = 1024;
    const int z = blockIdx.z;
    const float* W = (z == 0) ? A0 : (z == 1) ? A1 : (z == 2) ? A2 : A3;
    unsigned short* dst = Wt + (size_t)z * E * E;
    __shared__ float t[32][33];
    const int n0 = blockIdx.x * 32, k0 = blockIdx.y * 32;
    const int tx = threadIdx.x & 31;
    const int ty = threadIdx.x >> 5;
#pragma unroll
    for (int i = 0; i < 4; i++)
        t[ty + 8 * i][tx] = W[(size_t)(k0 + ty + 8 * i) * E + (n0 + tx)];
    __syncthreads();
#pragma unroll
    for (int i = 0; i < 4; i++)
        dst[(size_t)(n0 + ty + 8 * i) * E + (k0 + tx)] = f2bf(t[tx][ty + 8 * i]);
}

// ---------------- bf16 MFMA GEMM (m97 structure): C = A[M][K] * Bt[N][K]^T ----------------
// EPI 1: fp32 = acc + resid   EPI 2: bf16 = gelu(acc+bias)
// EPI 3: fp32 = acc + bias + resid   EPI 5: bf16 QKV (Q cols pre-scaled)
template <int EPI>
__global__ __launch_bounds__(256) void gemm_kernel(
    const unsigned short* __restrict__ A, const unsigned short* __restrict__ Bt,
    const float* __restrict__ bias, const float* __restrict__ resid,
    void* __restrict__ out, int M, int N, int K)
{
    __shared__ unsigned short Al[128][64];
    __shared__ unsigned short Bl[128][64];
    const int tid = threadIdx.x;
    const int lane = tid & 63, wid = tid >> 6;
    const int wr = wid >> 1, wc = wid & 1;
    const int li = lane & 15, lg = lane >> 4;
    const int m0 = blockIdx.y * 128, n0 = blockIdx.x * 128;
    const int srow = lane >> 3;
    const int schunk = ((lane & 7) ^ srow) * 8;
    const unsigned short* Asrc = A + (size_t)(m0 + wid * 32 + srow) * K + schunk;
    const unsigned short* Bsrc = Bt + (size_t)(n0 + wid * 32 + srow) * K + schunk;
    f32x4 acc[4][4] = {};

    for (int k0 = 0; k0 < K; k0 += 64) {
        __syncthreads();
#pragma unroll
        for (int i = 0; i < 4; i++) {
            gload_lds16(Asrc + k0 + (size_t)i * 8 * K, &Al[wid * 32 + i * 8][0]);
            gload_lds16(Bsrc + k0 + (size_t)i * 8 * K, &Bl[wid * 32 + i * 8][0]);
        }
        __syncthreads();
#pragma unroll
        for (int ks = 0; ks < 2; ks++) {
            bf16x8 af[4], bfr[4];
#pragma unroll
            for (int m = 0; m < 4; m++)
                af[m] = *reinterpret_cast<const bf16x8*>(
                    &Al[wr * 64 + m * 16 + li][((ks * 4 + lg) ^ (li & 7)) * 8]);
#pragma unroll
            for (int n = 0; n < 4; n++)
                bfr[n] = *reinterpret_cast<const bf16x8*>(
                    &Bl[wc * 64 + n * 16 + li][((ks * 4 + lg) ^ (li & 7)) * 8]);
#pragma unroll
            for (int m = 0; m < 4; m++)
#pragma unroll
                for (int n = 0; n < 4; n++)
                    acc[m][n] = __builtin_amdgcn_mfma_f32_16x16x32_bf16(af[m], bfr[n], acc[m][n], 0, 0, 0);
        }
    }

#pragma unroll
    for (int m = 0; m < 4; m++) {
#pragma unroll
        for (int r = 0; r < 4; r++) {
            const int row = m0 + wr * 64 + m * 16 + lg * 4 + r;
#pragma unroll
            for (int n = 0; n < 4; n++) {
                const int col = n0 + wc * 64 + n * 16 + li;
                float v = acc[m][n][r];
                if constexpr (EPI == 1) {
                    reinterpret_cast<float*>(out)[(size_t)row * N + col] =
                        v + resid[(size_t)row * N + col];
                } else if constexpr (EPI == 2) {
                    v += bias[col];
                    float a2 = 1.5957691216f * (v + 0.044715f * v * v * v);
                    a2 = fminf(a2, 80.0f);
                    const float t = __expf(a2);
                    v = v * t * __builtin_amdgcn_rcpf(t + 1.0f);
                    reinterpret_cast<unsigned short*>(out)[(size_t)row * N + col] = f2bf(v);
                } else if constexpr (EPI == 3) {
                    reinterpret_cast<float*>(out)[(size_t)row * N + col] =
                        v + bias[col] + resid[(size_t)row * N + col];
                } else {  // EPI 5: fused QKV, Q columns pre-scaled for exp2 softmax
                    const float sc = (col < 1024) ? QSCALE : 1.0f;
                    reinterpret_cast<unsigned short*>(out)[(size_t)row * N + col] = f2bf(v * sc);
                }
            }
        }
    }
}

// ---------------- Flash attention (causal), no-max exp2 softmax, 1 barrier/tile ----------------
// QKV [8192][3072] (Q pre-scaled by QSCALE). grid 1024 = 4 blocks/CU exactly resident.
__global__ __launch_bounds__(256, 4) void flash_kernel(
    const unsigned short* __restrict__ QKV, unsigned short* __restrict__ O)
{
    constexpr int C = 2048, HD3 = 3072, HD = 1024, NT = 32;
    __shared__ unsigned short Kl[2][64][64];  // [key][d], chunk XOR (row&7)
    __shared__ unsigned short Vt[2][64][64];  // [d][key], chunk XOR (row&7)^(row>>3)
    __shared__ unsigned short Pl[64][64];     // [q][key], chunk rotation +2*(row>>2)
    const int tid = threadIdx.x;
    const int lane = tid & 63, wid = tid >> 6;
    const int li = lane & 15, lg = lane >> 4;
    const int flat = blockIdx.x;
    const int bh = flat & 63;                // one head's 16 blocks share an XCD
    const int pair = flat >> 6;              // 0..15
    const int b = bh >> 4, h = bh & 15;
    const size_t baseQ = ((size_t)b * C) * HD3 + (size_t)h * 64;
    const size_t baseK = baseQ + 1024;
    const size_t baseV = baseQ + 2048;
    const size_t baseO = ((size_t)b * C) * HD + (size_t)h * 64;

    const int srow = lane >> 3;                       // 0..7
    const int sgc = ((lane & 7) ^ srow) * 8;          // K pre-swizzled global chunk
    const int vx = lane & 7;                          // V: d-block [vx*8, vx*8+8)

    const u16x8 onesu = {0x3F80, 0x3F80, 0x3F80, 0x3F80, 0x3F80, 0x3F80, 0x3F80, 0x3F80};
    const bf16x8 ones = __builtin_bit_cast(bf16x8, onesu);

    for (int half = 0; half < 2; half++) {
        const int qt = (half == 0) ? pair : (NT - 1 - pair);
        const int q0 = qt * 64;
        const int qrow = q0 + wid * 16 + li;
        const bf16x8 qa0 = *reinterpret_cast<const bf16x8*>(&QKV[baseQ + (size_t)qrow * HD3 + lg * 8]);
        const bf16x8 qa1 = *reinterpret_cast<const bf16x8*>(&QKV[baseQ + (size_t)qrow * HD3 + 32 + lg * 8]);
        const int myrow0 = q0 + wid * 16 + lg * 4;

        f32x4 acc[4] = {};
        f32x4 accl = {};
        int cur = 0;

        // stage a KV tile: K via global_load_lds, V via regs -> transposed swizzled store
        auto stage = [&](int k0s, int buf) {
#pragma unroll
            for (int i = 0; i < 2; i++)
                gload_lds16(&QKV[baseK + (size_t)(k0s + wid * 16 + i * 8 + srow) * HD3 + sgc],
                            &Kl[buf][wid * 16 + i * 8][0]);
#pragma unroll
            for (int i = 0; i < 2; i++) {
                const int lkey = 8 * wid + srow + 32 * i;
                const u16x8 vv = *reinterpret_cast<const u16x8*>(
                    &QKV[baseV + (size_t)(k0s + lkey) * HD3 + vx * 8]);
                const int vc = wid + 4 * i;  // lkey>>3
#pragma unroll
                for (int j = 0; j < 8; j++)
                    Vt[buf][vx * 8 + j][((vc ^ j ^ vx) & 7) * 8 + srow] = vv[j];
            }
        };

        // prologue: stage tile 0 into buf 0
        __syncthreads();
        stage(0, 0);
        __syncthreads();

        auto tile_body = [&](int t, bool diag, bool pre) {
            const int k0 = t * 64;
            u16x8 vr0, vr1;
            if (pre) {  // issue next-tile loads early (hide under compute)
                const int kn = k0 + 64;
#pragma unroll
                for (int i = 0; i < 2; i++)
                    gload_lds16(&QKV[baseK + (size_t)(kn + wid * 16 + i * 8 + srow) * HD3 + sgc],
                                &Kl[cur ^ 1][wid * 16 + i * 8][0]);
                vr0 = *reinterpret_cast<const u16x8*>(
                    &QKV[baseV + (size_t)(kn + 8 * wid + srow) * HD3 + vx * 8]);
                vr1 = *reinterpret_cast<const u16x8*>(
                    &QKV[baseV + (size_t)(kn + 8 * wid + srow + 32) * HD3 + vx * 8]);
            }

            // S = Q K^T (Q pre-scaled; S in log2 domain)
            f32x4 s[4] = {};
            __builtin_amdgcn_s_setprio(1);
#pragma unroll
            for (int n = 0; n < 4; n++) {
                const int row = n * 16 + li;
                const bf16x8 kb0 = *reinterpret_cast<const bf16x8*>(
                    &Kl[cur][row][(lg ^ (li & 7)) * 8]);
                const bf16x8 kb1 = *reinterpret_cast<const bf16x8*>(
                    &Kl[cur][row][((4 + lg) ^ (li & 7)) * 8]);
                s[n] = __builtin_amdgcn_mfma_f32_16x16x32_bf16(qa0, kb0, s[n], 0, 0, 0);
                s[n] = __builtin_amdgcn_mfma_f32_16x16x32_bf16(qa1, kb1, s[n], 0, 0, 0);
            }
            __builtin_amdgcn_s_setprio(0);

            // P = exp2(S), causal zeroing on diag tile only; store to Pl (rotated chunks)
#pragma unroll
            for (int n = 0; n < 4; n++) {
#pragma unroll
                for (int r = 0; r < 4; r++) {
                    float pv = fexp2(s[n][r]);
                    if (diag) {
                        const int key = k0 + n * 16 + li;
                        if (key > myrow0 + r) pv = 0.0f;
                    }
                    Pl[wid * 16 + lg * 4 + r][((2 * n + (li >> 3) + 2 * lg) & 7) * 8 + (li & 7)] = f2bf(pv);
                }
            }

            if (pre) {  // V regs have arrived by now; fill Vt[next]
#pragma unroll
                for (int j = 0; j < 8; j++)
                    Vt[cur ^ 1][vx * 8 + j][((wid ^ j ^ vx) & 7) * 8 + srow] = vr0[j];
#pragma unroll
                for (int j = 0; j < 8; j++)
                    Vt[cur ^ 1][vx * 8 + j][(((wid + 4) ^ j ^ vx) & 7) * 8 + srow] = vr1[j];
            }

            // O += P V ; row-sums via ones-MFMA
            __builtin_amdgcn_s_setprio(1);
#pragma unroll
            for (int ks = 0; ks < 2; ks++) {
                const bf16x8 pa = *reinterpret_cast<const bf16x8*>(
                    &Pl[wid * 16 + li][((ks * 4 + lg + 2 * (li >> 2)) & 7) * 8]);
#pragma unroll
                for (int n = 0; n < 4; n++) {
                    const int row = n * 16 + li;
                    const bf16x8 vb = *reinterpret_cast<const bf16x8*>(
                        &Vt[cur][row][(((ks * 4 + lg) ^ (row & 7) ^ (row >> 3)) & 7) * 8]);
                    acc[n] = __builtin_amdgcn_mfma_f32_16x16x32_bf16(pa, vb, acc[n], 0, 0, 0);
                }
                accl = __builtin_amdgcn_mfma_f32_16x16x32_bf16(pa, ones, accl, 0, 0, 0);
            }
            __builtin_amdgcn_s_setprio(0);

            __syncthreads();  // staging done (vmcnt+lgkm drained), buffers flip
            cur ^= 1;
        };

        for (int t = 0; t < qt; t++) tile_body(t, false, true);
        tile_body(qt, true, false);

        // epilogue: O = acc / l
#pragma unroll
        for (int r = 0; r < 4; r++) {
            const float inv = 1.0f / accl[r];
            const int row = myrow0 + r;
#pragma unroll
            for (int n = 0; n < 4; n++)
                O[baseO + (size_t)row * HD + n * 16 + li] = f2bf(acc[n][r] * inv);
        }
    }
}

// ---------------- launch ----------------
extern "C" void kernel_launch(void* const* d_in, const int* in_sizes, int n_in,
                              void* d_out, int out_size, void* d_ws, size_t ws_size,
                              hipStream_t stream) {
    constexpr int B = 4, C = 2048, E = 1024, H = 16, FF = 4096;
    constexpr int M = B * C;  // 8192

    const float* x     = (const float*)d_in[0];
    const float* ln1_g = (const float*)d_in[1];
    const float* ln1_b = (const float*)d_in[2];
    const float* Wq    = (const float*)d_in[3];
    const float* Wk    = (const float*)d_in[4];
    const float* Wv    = (const float*)d_in[5];
    const float* Wo    = (const float*)d_in[6];
    const float* ln2_g = (const float*)d_in[7];
    const float* ln2_b = (const float*)d_in[8];
    const float* W1    = (const float*)d_in[9];
    const float* b1    = (const float*)d_in[10];
    const float* W2    = (const float*)d_in[11];
    const float* b2    = (const float*)d_in[12];

    char* p = (char*)d_ws;
    auto alloc = [&](size_t bytes) { void* r = (void*)p; p += (bytes + 255) & ~(size_t)255; return r; };
    unsigned short* WqT  = (unsigned short*)alloc((size_t)E * E * 2);   // Wq/Wk/Wv/Wo contiguous
    unsigned short* WkT  = (unsigned short*)alloc((size_t)E * E * 2);
    unsigned short* WvT  = (unsigned short*)alloc((size_t)E * E * 2);
    unsigned short* WoT  = (unsigned short*)alloc((size_t)E * E * 2);
    unsigned short* W1T  = (unsigned short*)alloc((size_t)E * FF * 2);
    unsigned short* W2T  = (unsigned short*)alloc((size_t)FF * E * 2);
    unsigned short* hb   = (unsigned short*)alloc((size_t)M * E * 2);
    unsigned short* QKVb = (unsigned short*)alloc((size_t)M * 3 * E * 2);
    unsigned short* attn = (unsigned short*)alloc((size_t)M * E * 2);
    float*          x1   = (float*)alloc((size_t)M * E * 4);
    unsigned short* h2   = (unsigned short*)alloc((size_t)M * E * 2);
    unsigned short* ff   = (unsigned short*)alloc((size_t)M * FF * 2);
    (void)WkT; (void)WvT;

    // weight conversion / transpose (4 square ones fused)
    convT4_kernel<<<dim3(E / 32, E / 32, 4), 256, 0, stream>>>(Wq, Wk, Wv, Wo, WqT);
    convT_kernel<<<dim3(FF / 32, E / 32), 256, 0, stream>>>(W1, W1T, E, FF);
    convT_kernel<<<dim3(E / 32, FF / 32), 256, 0, stream>>>(W2, W2T, FF, E);

    // LN1
    ln_kernel<<<M, 256, 0, stream>>>(x, ln1_g, ln1_b, hb);

    // fused QKV projection (N=3072), Q columns pre-scaled
    gemm_kernel<5><<<dim3(3 * E / 128, M / 128), 256, 0, stream>>>(hb, WqT, nullptr, nullptr, QKVb, M, 3 * E, E);

    // attention
    flash_kernel<<<dim3(1024), 256, 0, stream>>>(QKVb, attn);

    // output projection + residual
    gemm_kernel<1><<<dim3(E / 128, M / 128), 256, 0, stream>>>(attn, WoT, nullptr, x, x1, M, E, E);

    // LN2
    ln_kernel<<<M, 256, 0, stream>>>(x1, ln2_g, ln2_b, h2);

    // FFN
    gemm_kernel<2><<<dim3(FF / 128, M / 128), 256, 0, stream>>>(h2, W1T, b1, nullptr, ff, M, FF, E);
    gemm_kernel<3><<<dim3(E / 128, M / 128), 256, 0, stream>>>(ff, W2T, b2, x1, d_out, M, E, FF);
}